// Round 1
// baseline (1773.240 us; speedup 1.0000x reference)
//
#include <hip/hip_runtime.h>
#include <hip/hip_bf16.h>
#include <cstdio>

typedef short s16x8 __attribute__((ext_vector_type(8)));
typedef unsigned short u16x8 __attribute__((ext_vector_type(8)));
typedef float f32x4 __attribute__((ext_vector_type(4)));

#define B_TOK 8192      // b*l
#define DDIM 1024
#define INTER 2816
#define NEXP 8

__device__ __forceinline__ unsigned short f2bf(float f) {
    unsigned int u = __float_as_uint(f);
    unsigned int r = u + 0x7fffu + ((u >> 16) & 1u);
    return (unsigned short)(r >> 16);
}

__device__ __forceinline__ void gload_lds16(const void* g, void* l) {
    __builtin_amdgcn_global_load_lds(
        (const __attribute__((address_space(1))) unsigned int*)g,
        (__attribute__((address_space(3))) unsigned int*)l, 16, 0, 0);
}

// ---------------- conversion kernels ----------------

__global__ void convert_f32_bf16(const float* __restrict__ src,
                                 unsigned short* __restrict__ dst, int n) {
    int i = (blockIdx.x * blockDim.x + threadIdx.x) * 8;
    if (i + 8 > n) return;
    float4 a = *(const float4*)(src + i);
    float4 b = *(const float4*)(src + i + 4);
    u16x8 o;
    o[0] = f2bf(a.x); o[1] = f2bf(a.y); o[2] = f2bf(a.z); o[3] = f2bf(a.w);
    o[4] = f2bf(b.x); o[5] = f2bf(b.y); o[6] = f2bf(b.z); o[7] = f2bf(b.w);
    *(u16x8*)(dst + i) = o;
}

// src: K x N row-major (per expert, z), dst: N x K bf16
__global__ void transpose_convert(const float* __restrict__ src,
                                  unsigned short* __restrict__ dst,
                                  int K, int N) {
    __shared__ float tile[32][33];
    int e = blockIdx.z;
    src += (size_t)e * K * N;
    dst += (size_t)e * K * N;
    int n0 = blockIdx.x * 32, k0 = blockIdx.y * 32;
    int x = threadIdx.x, y = threadIdx.y;  // 32 x 8
#pragma unroll
    for (int j = 0; j < 4; ++j) {
        int k = k0 + y * 4 + j;
        tile[y * 4 + j][x] = src[(size_t)k * N + n0 + x];
    }
    __syncthreads();
#pragma unroll
    for (int j = 0; j < 4; ++j) {
        int n = n0 + y * 4 + j;
        dst[(size_t)n * K + k0 + x] = f2bf(tile[x][y * 4 + j]);
    }
}

// ---------------- gating ----------------
// one wave per token; exact fp32 logits, top-2 (lowest index wins ties), softmax
__global__ void gating_kernel(const float* __restrict__ h,
                              const float* __restrict__ gw,
                              float* __restrict__ route) {
    int wid = threadIdx.x >> 6, lane = threadIdx.x & 63;
    int t = blockIdx.x * 4 + wid;
    if (t >= B_TOK) return;
    const float* hp = h + (size_t)t * DDIM + lane * 16;
    const float* gp = gw + (size_t)lane * 16 * NEXP;
    float s[8] = {0, 0, 0, 0, 0, 0, 0, 0};
#pragma unroll
    for (int kk = 0; kk < 16; ++kk) {
        float hv = hp[kk];
#pragma unroll
        for (int e = 0; e < 8; ++e) s[e] += hv * gp[kk * 8 + e];
    }
#pragma unroll
    for (int off = 32; off > 0; off >>= 1) {
#pragma unroll
        for (int e = 0; e < 8; ++e) s[e] += __shfl_down(s[e], off);
    }
    if (lane == 0) {
        float m0 = -1e30f; int i0 = 0;
#pragma unroll
        for (int e = 0; e < 8; ++e) if (s[e] > m0) { m0 = s[e]; i0 = e; }
        float m1 = -1e30f; int i1 = -1;
#pragma unroll
        for (int e = 0; e < 8; ++e) if (e != i0 && s[e] > m1) { m1 = s[e]; i1 = e; }
        float d = __expf(m1 - m0);
        float w0 = 1.f / (1.f + d);
        float w1 = d * w0;
#pragma unroll
        for (int e = 0; e < 8; ++e)
            route[(size_t)t * 8 + e] = (e == i0) ? w0 : ((e == i1) ? w1 : 0.f);
    }
}

__global__ void loss_kernel(const float* __restrict__ route, float* __restrict__ lb) {
    __shared__ float ps[8];
    int tid = threadIdx.x;
    if (tid < 8) ps[tid] = 0.f;
    __syncthreads();
    float s[8] = {0, 0, 0, 0, 0, 0, 0, 0};
    for (int t = tid; t < B_TOK; t += 256) {
        const float* rp = route + (size_t)t * 8;  // route base is 4B-misaligned for float4 -> scalar
#pragma unroll
        for (int e = 0; e < 8; ++e) s[e] += rp[e];
    }
#pragma unroll
    for (int e = 0; e < 8; ++e) atomicAdd(&ps[e], s[e]);
    __syncthreads();
    if (tid == 0) {
        float acc = 0.f;
#pragma unroll
        for (int e = 0; e < 8; ++e) {
            float p = ps[e] / (float)B_TOK;
            acc += p * p;
        }
        lb[0] = 0.01f * acc;
    }
}

// ---------------- GEMM1: g/u dual with fused silu epilogue ----------------
// A: [8192][1024] bf16, Bg/Bu: [2816][1024] bf16 (N-major), act: [8192][2816] bf16
__global__ __launch_bounds__(256, 2) void gemm1_dual(
    const unsigned short* __restrict__ A,
    const unsigned short* __restrict__ Bg,
    const unsigned short* __restrict__ Bu,
    unsigned short* __restrict__ act) {
    __shared__ unsigned short sA[128 * 32];
    __shared__ unsigned short sG[128 * 32];
    __shared__ unsigned short sU[128 * 32];
    const int tid = threadIdx.x, wid = tid >> 6, lane = tid & 63;
    const int wr = wid >> 1, wc = wid & 1;
    const int rowBase = blockIdx.x * 128, colBase = blockIdx.y * 128;

    f32x4 accG[4][4], accU[4][4];
#pragma unroll
    for (int i = 0; i < 4; ++i)
#pragma unroll
        for (int j = 0; j < 4; ++j) { accG[i][j] = (f32x4)(0.f); accU[i][j] = (f32x4)(0.f); }

    const int c0 = wid, c1 = wid + 4;
    const int srow = lane >> 2;
    const int skoff = (lane & 3) * 8;
    const int rA = (lane & 15) * 32 + (lane >> 4) * 8;

    for (int k0 = 0; k0 < DDIM; k0 += 32) {
        gload_lds16(A + (size_t)(rowBase + c0 * 16 + srow) * DDIM + k0 + skoff, sA + c0 * 512);
        gload_lds16(A + (size_t)(rowBase + c1 * 16 + srow) * DDIM + k0 + skoff, sA + c1 * 512);
        gload_lds16(Bg + (size_t)(colBase + c0 * 16 + srow) * DDIM + k0 + skoff, sG + c0 * 512);
        gload_lds16(Bg + (size_t)(colBase + c1 * 16 + srow) * DDIM + k0 + skoff, sG + c1 * 512);
        gload_lds16(Bu + (size_t)(colBase + c0 * 16 + srow) * DDIM + k0 + skoff, sU + c0 * 512);
        gload_lds16(Bu + (size_t)(colBase + c1 * 16 + srow) * DDIM + k0 + skoff, sU + c1 * 512);
        asm volatile("s_waitcnt vmcnt(0)" ::: "memory");
        __syncthreads();

        s16x8 a[4], bg[4], bu[4];
#pragma unroll
        for (int mf = 0; mf < 4; ++mf)
            a[mf] = *(const s16x8*)&sA[(wr * 64 + mf * 16) * 32 + rA];
#pragma unroll
        for (int nf = 0; nf < 4; ++nf) {
            bg[nf] = *(const s16x8*)&sG[(wc * 64 + nf * 16) * 32 + rA];
            bu[nf] = *(const s16x8*)&sU[(wc * 64 + nf * 16) * 32 + rA];
        }
#pragma unroll
        for (int mf = 0; mf < 4; ++mf)
#pragma unroll
            for (int nf = 0; nf < 4; ++nf) {
                accG[mf][nf] = __builtin_amdgcn_mfma_f32_16x16x32_bf16(a[mf], bg[nf], accG[mf][nf], 0, 0, 0);
                accU[mf][nf] = __builtin_amdgcn_mfma_f32_16x16x32_bf16(a[mf], bu[nf], accU[mf][nf], 0, 0, 0);
            }
        __syncthreads();
    }

#pragma unroll
    for (int mf = 0; mf < 4; ++mf)
#pragma unroll
        for (int nf = 0; nf < 4; ++nf)
#pragma unroll
            for (int j = 0; j < 4; ++j) {
                int r = rowBase + wr * 64 + mf * 16 + (lane >> 4) * 4 + j;
                int c = colBase + wc * 64 + nf * 16 + (lane & 15);
                float g = accG[mf][nf][j], u = accU[mf][nf][j];
                float sg = 1.f / (1.f + __expf(-g));
                act[(size_t)r * INTER + c] = f2bf(g * sg * u);
            }
}

// ---------------- GEMM2: act @ wdT, route-weighted accumulate ----------------
// A: act [8192][2816] bf16, B: wdT[e] [1024][2816] bf16, out: [8192][1024] f32
__global__ __launch_bounds__(256, 2) void gemm2_acc(
    const unsigned short* __restrict__ A,
    const unsigned short* __restrict__ B,
    const float* __restrict__ route,
    float* __restrict__ out,
    int e, int first) {
    __shared__ unsigned short sA[128 * 32];
    __shared__ unsigned short sB[128 * 32];
    const int tid = threadIdx.x, wid = tid >> 6, lane = tid & 63;
    const int wr = wid >> 1, wc = wid & 1;
    const int rowBase = blockIdx.x * 128, colBase = blockIdx.y * 128;

    f32x4 acc[4][4];
#pragma unroll
    for (int i = 0; i < 4; ++i)
#pragma unroll
        for (int j = 0; j < 4; ++j) acc[i][j] = (f32x4)(0.f);

    const int c0 = wid, c1 = wid + 4;
    const int srow = lane >> 2;
    const int skoff = (lane & 3) * 8;
    const int rA = (lane & 15) * 32 + (lane >> 4) * 8;

    for (int k0 = 0; k0 < INTER; k0 += 32) {
        gload_lds16(A + (size_t)(rowBase + c0 * 16 + srow) * INTER + k0 + skoff, sA + c0 * 512);
        gload_lds16(A + (size_t)(rowBase + c1 * 16 + srow) * INTER + k0 + skoff, sA + c1 * 512);
        gload_lds16(B + (size_t)(colBase + c0 * 16 + srow) * INTER + k0 + skoff, sB + c0 * 512);
        gload_lds16(B + (size_t)(colBase + c1 * 16 + srow) * INTER + k0 + skoff, sB + c1 * 512);
        asm volatile("s_waitcnt vmcnt(0)" ::: "memory");
        __syncthreads();

        s16x8 a[4], b[4];
#pragma unroll
        for (int mf = 0; mf < 4; ++mf)
            a[mf] = *(const s16x8*)&sA[(wr * 64 + mf * 16) * 32 + rA];
#pragma unroll
        for (int nf = 0; nf < 4; ++nf)
            b[nf] = *(const s16x8*)&sB[(wc * 64 + nf * 16) * 32 + rA];
#pragma unroll
        for (int mf = 0; mf < 4; ++mf)
#pragma unroll
            for (int nf = 0; nf < 4; ++nf)
                acc[mf][nf] = __builtin_amdgcn_mfma_f32_16x16x32_bf16(a[mf], b[nf], acc[mf][nf], 0, 0, 0);
        __syncthreads();
    }

#pragma unroll
    for (int mf = 0; mf < 4; ++mf)
#pragma unroll
        for (int j = 0; j < 4; ++j) {
            int r = rowBase + wr * 64 + mf * 16 + (lane >> 4) * 4 + j;
            float w = route[(size_t)r * 8 + e];
#pragma unroll
            for (int nf = 0; nf < 4; ++nf) {
                int c = colBase + wc * 64 + nf * 16 + (lane & 15);
                size_t o = (size_t)r * DDIM + c;
                float v = acc[mf][nf][j] * w;
                if (!first) v += out[o];
                out[o] = v;
            }
        }
}

// ---------------- host ----------------

extern "C" void kernel_launch(void* const* d_in, const int* in_sizes, int n_in,
                              void* d_out, int out_size, void* d_ws, size_t ws_size,
                              hipStream_t stream) {
    const float* h = (const float*)d_in[0];
    const float* gate_w = (const float*)d_in[1];
    const float* wg = (const float*)d_in[2];
    const float* wu = (const float*)d_in[3];
    const float* wd = (const float*)d_in[4];

    float* out = (float*)d_out;                       // results: 8192*1024
    float* lb = out + (size_t)B_TOK * DDIM;           // 1
    float* route = lb + 1;                            // 8192*8

    const size_t SZ_HB = (size_t)B_TOK * DDIM * 2;            // 16,777,216
    const size_t SZ_W = (size_t)NEXP * DDIM * INTER * 2;      // 46,137,344
    const size_t SZ_ACT = (size_t)B_TOK * INTER * 2;          // 46,137,344
    const size_t NEED = SZ_HB + 3 * SZ_W + SZ_ACT;            // ~201.3 MB
    if (ws_size < NEED) {
        fprintf(stderr, "kernel_launch: ws too small: %zu < %zu\n", ws_size, NEED);
        return;
    }
    unsigned char* ws = (unsigned char*)d_ws;
    unsigned short* hb = (unsigned short*)ws;
    unsigned short* wgT = (unsigned short*)(ws + SZ_HB);
    unsigned short* wuT = (unsigned short*)(ws + SZ_HB + SZ_W);
    unsigned short* wdT = (unsigned short*)(ws + SZ_HB + 2 * SZ_W);
    unsigned short* act = (unsigned short*)(ws + SZ_HB + 3 * SZ_W);

    convert_f32_bf16<<<4096, 256, 0, stream>>>(h, hb, B_TOK * DDIM);
    dim3 tb(32, 8, 1);
    transpose_convert<<<dim3(INTER / 32, DDIM / 32, NEXP), tb, 0, stream>>>(wg, wgT, DDIM, INTER);
    transpose_convert<<<dim3(INTER / 32, DDIM / 32, NEXP), tb, 0, stream>>>(wu, wuT, DDIM, INTER);
    transpose_convert<<<dim3(DDIM / 32, INTER / 32, NEXP), tb, 0, stream>>>(wd, wdT, INTER, DDIM);
    gating_kernel<<<B_TOK / 4, 256, 0, stream>>>(h, gate_w, route);
    loss_kernel<<<1, 256, 0, stream>>>(route, lb);

    for (int e = 0; e < NEXP; ++e) {
        gemm1_dual<<<dim3(B_TOK / 128, INTER / 128), 256, 0, stream>>>(
            hb, wgT + (size_t)e * DDIM * INTER, wuT + (size_t)e * DDIM * INTER, act);
        gemm2_acc<<<dim3(B_TOK / 128, DDIM / 128), 256, 0, stream>>>(
            act, wdT + (size_t)e * DDIM * INTER, route, out, e, e == 0 ? 1 : 0);
    }
}

// Round 2
// 845.668 us; speedup vs baseline: 2.0969x; 2.0969x over previous
//
#include <hip/hip_runtime.h>
#include <hip/hip_bf16.h>
#include <cstdio>

typedef short s16x8 __attribute__((ext_vector_type(8)));
typedef unsigned short u16x8 __attribute__((ext_vector_type(8)));
typedef float f32x4 __attribute__((ext_vector_type(4)));

#define B_TOK 8192      // b*l
#define DDIM 1024
#define INTER 2816
#define NEXP 8
#define CAP_TILES 136               // max sum ceil(cnt[e]/128) = 135; capacity 136
#define CAP_SLOTS (CAP_TILES * 128) // 17408

__device__ __forceinline__ unsigned short f2bf(float f) {
    unsigned int u = __float_as_uint(f);
    unsigned int r = u + 0x7fffu + ((u >> 16) & 1u);
    return (unsigned short)(r >> 16);
}

__device__ __forceinline__ void gload_lds16(const void* g, void* l) {
    __builtin_amdgcn_global_load_lds(
        (const __attribute__((address_space(1))) unsigned int*)g,
        (__attribute__((address_space(3))) unsigned int*)l, 16, 0, 0);
}

// ---------------- conversion kernels ----------------

__global__ void convert_f32_bf16(const float* __restrict__ src,
                                 unsigned short* __restrict__ dst, int n) {
    int i = (blockIdx.x * blockDim.x + threadIdx.x) * 8;
    if (i + 8 > n) return;
    float4 a = *(const float4*)(src + i);
    float4 b = *(const float4*)(src + i + 4);
    u16x8 o;
    o[0] = f2bf(a.x); o[1] = f2bf(a.y); o[2] = f2bf(a.z); o[3] = f2bf(a.w);
    o[4] = f2bf(b.x); o[5] = f2bf(b.y); o[6] = f2bf(b.z); o[7] = f2bf(b.w);
    *(u16x8*)(dst + i) = o;
}

// src: K x N row-major (per expert, z), dst: N x K bf16
__global__ void transpose_convert(const float* __restrict__ src,
                                  unsigned short* __restrict__ dst,
                                  int K, int N) {
    __shared__ float tile[32][33];
    int e = blockIdx.z;
    src += (size_t)e * K * N;
    dst += (size_t)e * K * N;
    int n0 = blockIdx.x * 32, k0 = blockIdx.y * 32;
    int x = threadIdx.x, y = threadIdx.y;  // 32 x 8
#pragma unroll
    for (int j = 0; j < 4; ++j) {
        int k = k0 + y * 4 + j;
        tile[y * 4 + j][x] = src[(size_t)k * N + n0 + x];
    }
    __syncthreads();
#pragma unroll
    for (int j = 0; j < 4; ++j) {
        int n = n0 + y * 4 + j;
        dst[(size_t)n * K + k0 + x] = f2bf(tile[x][y * 4 + j]);
    }
}

// ---------------- gating ----------------
// one wave per token; exact fp32 logits, top-2 (lowest index wins ties), softmax
// Additionally emits sel01 / wpair per token and per-expert counts.
__global__ void gating_kernel(const float* __restrict__ h,
                              const float* __restrict__ gw,
                              float* __restrict__ route,
                              int* __restrict__ sel01,
                              float2* __restrict__ wpair,
                              int* __restrict__ counts) {
    int wid = threadIdx.x >> 6, lane = threadIdx.x & 63;
    int t = blockIdx.x * 4 + wid;
    if (t >= B_TOK) return;
    const float* hp = h + (size_t)t * DDIM + lane * 16;
    const float* gp = gw + (size_t)lane * 16 * NEXP;
    float s[8] = {0, 0, 0, 0, 0, 0, 0, 0};
#pragma unroll
    for (int kk = 0; kk < 16; ++kk) {
        float hv = hp[kk];
#pragma unroll
        for (int e = 0; e < 8; ++e) s[e] += hv * gp[kk * 8 + e];
    }
#pragma unroll
    for (int off = 32; off > 0; off >>= 1) {
#pragma unroll
        for (int e = 0; e < 8; ++e) s[e] += __shfl_down(s[e], off);
    }
    if (lane == 0) {
        float m0 = -1e30f; int i0 = 0;
#pragma unroll
        for (int e = 0; e < 8; ++e) if (s[e] > m0) { m0 = s[e]; i0 = e; }
        float m1 = -1e30f; int i1 = -1;
#pragma unroll
        for (int e = 0; e < 8; ++e) if (e != i0 && s[e] > m1) { m1 = s[e]; i1 = e; }
        float d = __expf(m1 - m0);
        float w0 = 1.f / (1.f + d);
        float w1 = d * w0;
#pragma unroll
        for (int e = 0; e < 8; ++e)
            route[(size_t)t * 8 + e] = (e == i0) ? w0 : ((e == i1) ? w1 : 0.f);
        sel01[t] = i0 | (i1 << 8);
        wpair[t] = make_float2(w0, w1);
        atomicAdd(&counts[i0], 1);
        atomicAdd(&counts[i1], 1);
    }
}

// single block: per-expert 128-aligned slot offsets + tile -> (expert, slot0) table
__global__ void setup_kernel(const int* __restrict__ counts,
                             int* __restrict__ aoff,
                             int* __restrict__ tile_e,
                             int* __restrict__ tile_s0) {
    __shared__ int s_aoff[8], s_t0[9];
    if (threadIdx.x == 0) {
        int acc_slot = 0, acc_tile = 0;
        for (int e = 0; e < 8; ++e) {
            s_aoff[e] = acc_slot;
            s_t0[e] = acc_tile;
            int nt = (counts[e] + 127) >> 7;
            acc_slot += nt << 7;
            acc_tile += nt;
        }
        s_t0[8] = acc_tile;
        for (int e = 0; e < 8; ++e) aoff[e] = s_aoff[e];
    }
    __syncthreads();
    int t = threadIdx.x;
    if (t < CAP_TILES) {
        int e = -1, s0 = 0;
        for (int x = 0; x < 8; ++x)
            if (t >= s_t0[x] && t < s_t0[x + 1]) { e = x; s0 = s_aoff[x] + ((t - s_t0[x]) << 7); }
        tile_e[t] = e;
        tile_s0[t] = s0;
    }
}

__global__ void fill_kernel(const int* __restrict__ sel01,
                            const float2* __restrict__ wpair,
                            const int* __restrict__ aoff,
                            int* __restrict__ rank,
                            int* __restrict__ idx,
                            float* __restrict__ wslot) {
    int t = blockIdx.x * 256 + threadIdx.x;
    if (t >= B_TOK) return;
    int s = sel01[t];
    float2 w = wpair[t];
    int e0 = s & 0xff, e1 = (s >> 8) & 0xff;
    int p0 = atomicAdd(&rank[e0], 1);
    int sl0 = aoff[e0] + p0;
    idx[sl0] = t; wslot[sl0] = w.x;
    int p1 = atomicAdd(&rank[e1], 1);
    int sl1 = aoff[e1] + p1;
    idx[sl1] = t; wslot[sl1] = w.y;
}

__global__ void loss_kernel(const float* __restrict__ route, float* __restrict__ lb) {
    __shared__ float ps[8];
    int tid = threadIdx.x;
    if (tid < 8) ps[tid] = 0.f;
    __syncthreads();
    float s[8] = {0, 0, 0, 0, 0, 0, 0, 0};
    for (int t = tid; t < B_TOK; t += 256) {
        const float* rp = route + (size_t)t * 8;
#pragma unroll
        for (int e = 0; e < 8; ++e) s[e] += rp[e];
    }
#pragma unroll
    for (int e = 0; e < 8; ++e) atomicAdd(&ps[e], s[e]);
    __syncthreads();
    if (tid == 0) {
        float acc = 0.f;
#pragma unroll
        for (int e = 0; e < 8; ++e) {
            float p = ps[e] / (float)B_TOK;
            acc += p * p;
        }
        lb[0] = 0.01f * acc;
    }
}

// ---------------- GEMM1 sparse: gathered rows, g/u dual, fused silu ----------------
// A: hb [8192][1024] bf16 (gathered via idx), Bg/Bu: [E][2816][1024] bf16,
// act: [CAP_SLOTS][2816] bf16
__global__ __launch_bounds__(256, 2) void gemm1_sparse(
    const unsigned short* __restrict__ A,
    const unsigned short* __restrict__ Bg,
    const unsigned short* __restrict__ Bu,
    const int* __restrict__ tile_e,
    const int* __restrict__ tile_s0,
    const int* __restrict__ idx,
    unsigned short* __restrict__ act) {
    int e = tile_e[blockIdx.x];
    if (e < 0) return;
    const int slot0 = tile_s0[blockIdx.x];
    Bg += (size_t)e * DDIM * INTER;
    Bu += (size_t)e * DDIM * INTER;

    __shared__ unsigned short sA[128 * 32];
    __shared__ unsigned short sG[128 * 32];
    __shared__ unsigned short sU[128 * 32];
    const int tid = threadIdx.x, wid = tid >> 6, lane = tid & 63;
    const int wr = wid >> 1, wc = wid & 1;
    const int colBase = blockIdx.y * 128;

    f32x4 accG[4][4], accU[4][4];
#pragma unroll
    for (int i = 0; i < 4; ++i)
#pragma unroll
        for (int j = 0; j < 4; ++j) { accG[i][j] = (f32x4)(0.f); accU[i][j] = (f32x4)(0.f); }

    const int c0 = wid, c1 = wid + 4;
    const int srow = lane >> 2;
    const int skoff = (lane & 3) * 8;
    const int rA = (lane & 15) * 32 + (lane >> 4) * 8;

    // gather offsets are K-loop invariant: hoist
    const size_t gA0 = (size_t)idx[slot0 + c0 * 16 + srow] * DDIM + skoff;
    const size_t gA1 = (size_t)idx[slot0 + c1 * 16 + srow] * DDIM + skoff;
    const size_t gB0 = (size_t)(colBase + c0 * 16 + srow) * DDIM + skoff;
    const size_t gB1 = (size_t)(colBase + c1 * 16 + srow) * DDIM + skoff;

    for (int k0 = 0; k0 < DDIM; k0 += 32) {
        gload_lds16(A + gA0 + k0, sA + c0 * 512);
        gload_lds16(A + gA1 + k0, sA + c1 * 512);
        gload_lds16(Bg + gB0 + k0, sG + c0 * 512);
        gload_lds16(Bg + gB1 + k0, sG + c1 * 512);
        gload_lds16(Bu + gB0 + k0, sU + c0 * 512);
        gload_lds16(Bu + gB1 + k0, sU + c1 * 512);
        asm volatile("s_waitcnt vmcnt(0)" ::: "memory");
        __syncthreads();

        s16x8 a[4], bg[4], bu[4];
#pragma unroll
        for (int mf = 0; mf < 4; ++mf)
            a[mf] = *(const s16x8*)&sA[(wr * 64 + mf * 16) * 32 + rA];
#pragma unroll
        for (int nf = 0; nf < 4; ++nf) {
            bg[nf] = *(const s16x8*)&sG[(wc * 64 + nf * 16) * 32 + rA];
            bu[nf] = *(const s16x8*)&sU[(wc * 64 + nf * 16) * 32 + rA];
        }
#pragma unroll
        for (int mf = 0; mf < 4; ++mf)
#pragma unroll
            for (int nf = 0; nf < 4; ++nf) {
                accG[mf][nf] = __builtin_amdgcn_mfma_f32_16x16x32_bf16(a[mf], bg[nf], accG[mf][nf], 0, 0, 0);
                accU[mf][nf] = __builtin_amdgcn_mfma_f32_16x16x32_bf16(a[mf], bu[nf], accU[mf][nf], 0, 0, 0);
            }
        __syncthreads();
    }

#pragma unroll
    for (int mf = 0; mf < 4; ++mf)
#pragma unroll
        for (int nf = 0; nf < 4; ++nf)
#pragma unroll
            for (int j = 0; j < 4; ++j) {
                int r = slot0 + wr * 64 + mf * 16 + (lane >> 4) * 4 + j;
                int c = colBase + wc * 64 + nf * 16 + (lane & 15);
                float g = accG[mf][nf][j], u = accU[mf][nf][j];
                float sg = 1.f / (1.f + __expf(-g));
                act[(size_t)r * INTER + c] = f2bf(g * sg * u);
            }
}

// ---------------- GEMM2 sparse: act @ wdT, scatter-accumulate ----------------
// A: act [CAP_SLOTS][2816] bf16, B: wdT [E][1024][2816] bf16, out: [8192][1024] f32
__global__ __launch_bounds__(256, 2) void gemm2_sparse(
    const unsigned short* __restrict__ A,
    const unsigned short* __restrict__ Bd,
    const int* __restrict__ tile_e,
    const int* __restrict__ tile_s0,
    const int* __restrict__ idx,
    const float* __restrict__ wslot,
    float* __restrict__ out) {
    int e = tile_e[blockIdx.x];
    if (e < 0) return;
    const int slot0 = tile_s0[blockIdx.x];
    Bd += (size_t)e * DDIM * INTER;

    __shared__ unsigned short sA[128 * 32];
    __shared__ unsigned short sB[128 * 32];
    const int tid = threadIdx.x, wid = tid >> 6, lane = tid & 63;
    const int wr = wid >> 1, wc = wid & 1;
    const int colBase = blockIdx.y * 128;

    f32x4 acc[4][4];
#pragma unroll
    for (int i = 0; i < 4; ++i)
#pragma unroll
        for (int j = 0; j < 4; ++j) acc[i][j] = (f32x4)(0.f);

    const int c0 = wid, c1 = wid + 4;
    const int srow = lane >> 2;
    const int skoff = (lane & 3) * 8;
    const int rA = (lane & 15) * 32 + (lane >> 4) * 8;

    const size_t gA0 = (size_t)(slot0 + c0 * 16 + srow) * INTER + skoff;
    const size_t gA1 = (size_t)(slot0 + c1 * 16 + srow) * INTER + skoff;
    const size_t gB0 = (size_t)(colBase + c0 * 16 + srow) * INTER + skoff;
    const size_t gB1 = (size_t)(colBase + c1 * 16 + srow) * INTER + skoff;

    for (int k0 = 0; k0 < INTER; k0 += 32) {
        gload_lds16(A + gA0 + k0, sA + c0 * 512);
        gload_lds16(A + gA1 + k0, sA + c1 * 512);
        gload_lds16(Bd + gB0 + k0, sB + c0 * 512);
        gload_lds16(Bd + gB1 + k0, sB + c1 * 512);
        asm volatile("s_waitcnt vmcnt(0)" ::: "memory");
        __syncthreads();

        s16x8 a[4], b[4];
#pragma unroll
        for (int mf = 0; mf < 4; ++mf)
            a[mf] = *(const s16x8*)&sA[(wr * 64 + mf * 16) * 32 + rA];
#pragma unroll
        for (int nf = 0; nf < 4; ++nf)
            b[nf] = *(const s16x8*)&sB[(wc * 64 + nf * 16) * 32 + rA];
#pragma unroll
        for (int mf = 0; mf < 4; ++mf)
#pragma unroll
            for (int nf = 0; nf < 4; ++nf)
                acc[mf][nf] = __builtin_amdgcn_mfma_f32_16x16x32_bf16(a[mf], b[nf], acc[mf][nf], 0, 0, 0);
        __syncthreads();
    }

#pragma unroll
    for (int mf = 0; mf < 4; ++mf)
#pragma unroll
        for (int j = 0; j < 4; ++j) {
            int slot = slot0 + wr * 64 + mf * 16 + (lane >> 4) * 4 + j;
            int tok = idx[slot];
            float w = wslot[slot];
            if (w != 0.f) {
#pragma unroll
                for (int nf = 0; nf < 4; ++nf) {
                    int c = colBase + wc * 64 + nf * 16 + (lane & 15);
                    atomicAdd(&out[(size_t)tok * DDIM + c], acc[mf][nf][j] * w);
                }
            }
        }
}

// ---------------- host ----------------

extern "C" void kernel_launch(void* const* d_in, const int* in_sizes, int n_in,
                              void* d_out, int out_size, void* d_ws, size_t ws_size,
                              hipStream_t stream) {
    const float* h = (const float*)d_in[0];
    const float* gate_w = (const float*)d_in[1];
    const float* wg = (const float*)d_in[2];
    const float* wu = (const float*)d_in[3];
    const float* wd = (const float*)d_in[4];

    float* out = (float*)d_out;                       // results: 8192*1024
    float* lb = out + (size_t)B_TOK * DDIM;           // 1
    float* route = lb + 1;                            // 8192*8

    const size_t SZ_META = 1 << 20;                           // 1 MiB
    const size_t SZ_HB = (size_t)B_TOK * DDIM * 2;            // 16,777,216
    const size_t SZ_W = (size_t)NEXP * DDIM * INTER * 2;      // 46,137,344 per tensor
    const size_t SZ_ACT = (size_t)CAP_SLOTS * INTER * 2;      // 98,041,856
    const size_t NEED = SZ_META + SZ_HB + 2 * SZ_W + SZ_ACT;  // ~198.5 MiB
    if (ws_size < NEED) {
        fprintf(stderr, "kernel_launch: ws too small: %zu < %zu\n", ws_size, NEED);
        return;
    }
    char* ws = (char*)d_ws;
    // meta layout (within first 1 MiB)
    int* counts = (int*)(ws + 0);           // 8
    int* rank = (int*)(ws + 32);            // 8
    int* aoff = (int*)(ws + 64);            // 8
    int* tile_e = (int*)(ws + 128);         // 136
    int* tile_s0 = (int*)(ws + 1024);       // 136
    int* sel01 = (int*)(ws + 2048);         // 8192
    float2* wpair = (float2*)(ws + 34816);  // 8192
    int* idx = (int*)(ws + 100352);         // 17408
    float* wslot = (float*)(ws + 169984);   // 17408

    unsigned short* hb = (unsigned short*)(ws + SZ_META);
    unsigned short* wgT = (unsigned short*)(ws + SZ_META + SZ_HB);
    unsigned short* wuT = (unsigned short*)(ws + SZ_META + SZ_HB + SZ_W);
    unsigned short* act = (unsigned short*)(ws + SZ_META + SZ_HB + 2 * SZ_W);
    unsigned short* wdT = wgT;  // reuse wgT space AFTER gemm1 is done

    // zero metadata (counts/rank + idx/wslot padding) and the results region
    hipMemsetAsync(ws, 0, SZ_META, stream);
    hipMemsetAsync(out, 0, (size_t)B_TOK * DDIM * sizeof(float), stream);

    convert_f32_bf16<<<4096, 256, 0, stream>>>(h, hb, B_TOK * DDIM);
    dim3 tb(32, 8, 1);
    transpose_convert<<<dim3(INTER / 32, DDIM / 32, NEXP), tb, 0, stream>>>(wg, wgT, DDIM, INTER);
    transpose_convert<<<dim3(INTER / 32, DDIM / 32, NEXP), tb, 0, stream>>>(wu, wuT, DDIM, INTER);

    gating_kernel<<<B_TOK / 4, 256, 0, stream>>>(h, gate_w, route, sel01, wpair, counts);
    setup_kernel<<<1, 256, 0, stream>>>(counts, aoff, tile_e, tile_s0);
    fill_kernel<<<B_TOK / 256, 256, 0, stream>>>(sel01, wpair, aoff, rank, idx, wslot);
    loss_kernel<<<1, 256, 0, stream>>>(route, lb);

    gemm1_sparse<<<dim3(CAP_TILES, INTER / 128), 256, 0, stream>>>(
        hb, wgT, wuT, tile_e, tile_s0, idx, act);

    // now wgT/wuT are dead: transpose wd into that space
    transpose_convert<<<dim3(DDIM / 32, INTER / 32, NEXP), tb, 0, stream>>>(wd, wdT, INTER, DDIM);

    gemm2_sparse<<<dim3(CAP_TILES, DDIM / 128), 256, 0, stream>>>(
        act, wdT, tile_e, tile_s0, idx, wslot, out);
}

// Round 3
// 839.425 us; speedup vs baseline: 2.1124x; 1.0074x over previous
//
#include <hip/hip_runtime.h>
#include <hip/hip_bf16.h>
#include <cstdio>

typedef short s16x8 __attribute__((ext_vector_type(8)));
typedef unsigned short u16x8 __attribute__((ext_vector_type(8)));
typedef float f32x4 __attribute__((ext_vector_type(4)));

#define B_TOK 8192      // b*l
#define DDIM 1024
#define INTER 2816
#define NEXP 8
#define CAP_TILES 136               // max sum ceil(cnt[e]/128) = 135; capacity 136
#define CAP_SLOTS (CAP_TILES * 128) // 17408
#define NWG1 (CAP_TILES * (INTER / 128))  // 2992 = 8*374
#define NWG2 (CAP_TILES * (DDIM / 128))   // 1088 = 8*136

__device__ __forceinline__ unsigned short f2bf(float f) {
    unsigned int u = __float_as_uint(f);
    unsigned int r = u + 0x7fffu + ((u >> 16) & 1u);
    return (unsigned short)(r >> 16);
}

__device__ __forceinline__ void gload_lds16(const void* g, void* l) {
    __builtin_amdgcn_global_load_lds(
        (const __attribute__((address_space(1))) unsigned int*)g,
        (__attribute__((address_space(3))) unsigned int*)l, 16, 0, 0);
}

// ---------------- conversion kernels ----------------

__global__ void convert_f32_bf16(const float* __restrict__ src,
                                 unsigned short* __restrict__ dst, int n) {
    int i = (blockIdx.x * blockDim.x + threadIdx.x) * 8;
    if (i + 8 > n) return;
    float4 a = *(const float4*)(src + i);
    float4 b = *(const float4*)(src + i + 4);
    u16x8 o;
    o[0] = f2bf(a.x); o[1] = f2bf(a.y); o[2] = f2bf(a.z); o[3] = f2bf(a.w);
    o[4] = f2bf(b.x); o[5] = f2bf(b.y); o[6] = f2bf(b.z); o[7] = f2bf(b.w);
    *(u16x8*)(dst + i) = o;
}

// src: K x N f32 row-major (per expert via z), dst: N x K bf16. 64x64 tiles.
// float4 coalesced loads, u16x8 (16B) coalesced stores. LDS stride 70 ushorts
// (140B = 35 dwords): 8-row strides land on distinct bank bases -> <=2-way (free).
__global__ __launch_bounds__(256) void transpose_convert_v2(
    const float* __restrict__ src, unsigned short* __restrict__ dst,
    int K, int N) {
    __shared__ unsigned short tile[64][70];
    int e = blockIdx.z;
    src += (size_t)e * K * N;
    dst += (size_t)e * K * N;
    int n0 = blockIdx.x * 64, k0 = blockIdx.y * 64;
    int t = threadIdx.x;
    int lr = t >> 4;          // 0..15
    int lc = (t & 15) * 4;    // 0..60
#pragma unroll
    for (int p = 0; p < 4; ++p) {
        int kl = p * 16 + lr;
        float4 v = *(const float4*)(src + (size_t)(k0 + kl) * N + n0 + lc);
        tile[kl][lc + 0] = f2bf(v.x);
        tile[kl][lc + 1] = f2bf(v.y);
        tile[kl][lc + 2] = f2bf(v.z);
        tile[kl][lc + 3] = f2bf(v.w);
    }
    __syncthreads();
    int sn = t >> 3;          // 0..31
    int sk = (t & 7) * 8;     // 0..56
#pragma unroll
    for (int p = 0; p < 2; ++p) {
        int nl = p * 32 + sn;
        u16x8 o;
#pragma unroll
        for (int j = 0; j < 8; ++j) o[j] = tile[sk + j][nl];
        *(u16x8*)(dst + (size_t)(n0 + nl) * K + k0 + sk) = o;
    }
}

// ---------------- gating ----------------
// one wave per token; exact fp32 logits, top-2 (lowest index wins ties), softmax
__global__ void gating_kernel(const float* __restrict__ h,
                              const float* __restrict__ gw,
                              float* __restrict__ route,
                              int* __restrict__ sel01,
                              float2* __restrict__ wpair,
                              int* __restrict__ counts) {
    int wid = threadIdx.x >> 6, lane = threadIdx.x & 63;
    int t = blockIdx.x * 4 + wid;
    if (t >= B_TOK) return;
    const float* hp = h + (size_t)t * DDIM + lane * 16;
    const float* gp = gw + (size_t)lane * 16 * NEXP;
    float s[8] = {0, 0, 0, 0, 0, 0, 0, 0};
#pragma unroll
    for (int kk = 0; kk < 16; ++kk) {
        float hv = hp[kk];
#pragma unroll
        for (int e = 0; e < 8; ++e) s[e] += hv * gp[kk * 8 + e];
    }
#pragma unroll
    for (int off = 32; off > 0; off >>= 1) {
#pragma unroll
        for (int e = 0; e < 8; ++e) s[e] += __shfl_down(s[e], off);
    }
    if (lane == 0) {
        float m0 = -1e30f; int i0 = 0;
#pragma unroll
        for (int e = 0; e < 8; ++e) if (s[e] > m0) { m0 = s[e]; i0 = e; }
        float m1 = -1e30f; int i1 = -1;
#pragma unroll
        for (int e = 0; e < 8; ++e) if (e != i0 && s[e] > m1) { m1 = s[e]; i1 = e; }
        float d = __expf(m1 - m0);
        float w0 = 1.f / (1.f + d);
        float w1 = d * w0;
#pragma unroll
        for (int e = 0; e < 8; ++e)
            route[(size_t)t * 8 + e] = (e == i0) ? w0 : ((e == i1) ? w1 : 0.f);
        sel01[t] = i0 | (i1 << 8);
        wpair[t] = make_float2(w0, w1);
        atomicAdd(&counts[i0], 1);
        atomicAdd(&counts[i1], 1);
    }
}

// single block: per-expert 128-aligned slot offsets + tile -> (expert, slot0) table
__global__ void setup_kernel(const int* __restrict__ counts,
                             int* __restrict__ aoff,
                             int* __restrict__ tile_e,
                             int* __restrict__ tile_s0) {
    __shared__ int s_aoff[8], s_t0[9];
    if (threadIdx.x == 0) {
        int acc_slot = 0, acc_tile = 0;
        for (int e = 0; e < 8; ++e) {
            s_aoff[e] = acc_slot;
            s_t0[e] = acc_tile;
            int nt = (counts[e] + 127) >> 7;
            acc_slot += nt << 7;
            acc_tile += nt;
        }
        s_t0[8] = acc_tile;
        for (int e = 0; e < 8; ++e) aoff[e] = s_aoff[e];
    }
    __syncthreads();
    int t = threadIdx.x;
    if (t < CAP_TILES) {
        int e = -1, s0 = 0;
        for (int x = 0; x < 8; ++x)
            if (t >= s_t0[x] && t < s_t0[x + 1]) { e = x; s0 = s_aoff[x] + ((t - s_t0[x]) << 7); }
        tile_e[t] = e;
        tile_s0[t] = s0;
    }
}

__global__ void fill_kernel(const int* __restrict__ sel01,
                            const float2* __restrict__ wpair,
                            const int* __restrict__ aoff,
                            int* __restrict__ rank,
                            int* __restrict__ idx,
                            float* __restrict__ wslot) {
    int t = blockIdx.x * 256 + threadIdx.x;
    if (t >= B_TOK) return;
    int s = sel01[t];
    float2 w = wpair[t];
    int e0 = s & 0xff, e1 = (s >> 8) & 0xff;
    int p0 = atomicAdd(&rank[e0], 1);
    int sl0 = aoff[e0] + p0;
    idx[sl0] = t; wslot[sl0] = w.x;
    int p1 = atomicAdd(&rank[e1], 1);
    int sl1 = aoff[e1] + p1;
    idx[sl1] = t; wslot[sl1] = w.y;
}

__global__ void loss_kernel(const float* __restrict__ route, float* __restrict__ lb) {
    __shared__ float ps[8];
    int tid = threadIdx.x;
    if (tid < 8) ps[tid] = 0.f;
    __syncthreads();
    float s[8] = {0, 0, 0, 0, 0, 0, 0, 0};
    for (int t = tid; t < B_TOK; t += 256) {
        const float* rp = route + (size_t)t * 8;
#pragma unroll
        for (int e = 0; e < 8; ++e) s[e] += rp[e];
    }
#pragma unroll
    for (int e = 0; e < 8; ++e) atomicAdd(&ps[e], s[e]);
    __syncthreads();
    if (tid == 0) {
        float acc = 0.f;
#pragma unroll
        for (int e = 0; e < 8; ++e) {
            float p = ps[e] / (float)B_TOK;
            acc += p * p;
        }
        lb[0] = 0.01f * acc;
    }
}

// ---------------- GEMM1 sparse: gathered rows, g/u dual, fused silu ----------------
// grid: 1-D NWG1, XCD-bijective swizzle (tile varies fastest within an XCD chunk
// so each expert's 512KB B-panel stays L2-resident across its ~17 row-tiles)
__global__ __launch_bounds__(256, 2) void gemm1_sparse(
    const unsigned short* __restrict__ A,
    const unsigned short* __restrict__ Bg,
    const unsigned short* __restrict__ Bu,
    const int* __restrict__ tile_e,
    const int* __restrict__ tile_s0,
    const int* __restrict__ idx,
    unsigned short* __restrict__ act) {
    const int lin = blockIdx.x;
    const int swz = (lin & 7) * (NWG1 / 8) + (lin >> 3);
    const int tileId = swz % CAP_TILES;
    const int colBase = (swz / CAP_TILES) * 128;
    int e = tile_e[tileId];
    if (e < 0) return;
    const int slot0 = tile_s0[tileId];
    Bg += (size_t)e * DDIM * INTER;
    Bu += (size_t)e * DDIM * INTER;

    __shared__ unsigned short sA[128 * 32];
    __shared__ unsigned short sG[128 * 32];
    __shared__ unsigned short sU[128 * 32];
    const int tid = threadIdx.x, wid = tid >> 6, lane = tid & 63;
    const int wr = wid >> 1, wc = wid & 1;

    f32x4 accG[4][4], accU[4][4];
#pragma unroll
    for (int i = 0; i < 4; ++i)
#pragma unroll
        for (int j = 0; j < 4; ++j) { accG[i][j] = (f32x4)(0.f); accU[i][j] = (f32x4)(0.f); }

    const int c0 = wid, c1 = wid + 4;
    const int srow = lane >> 2;
    const int skoff = (lane & 3) * 8;
    const int rA = (lane & 15) * 32 + (lane >> 4) * 8;

    // gather offsets are K-loop invariant: hoist
    const size_t gA0 = (size_t)idx[slot0 + c0 * 16 + srow] * DDIM + skoff;
    const size_t gA1 = (size_t)idx[slot0 + c1 * 16 + srow] * DDIM + skoff;
    const size_t gB0 = (size_t)(colBase + c0 * 16 + srow) * DDIM + skoff;
    const size_t gB1 = (size_t)(colBase + c1 * 16 + srow) * DDIM + skoff;

    for (int k0 = 0; k0 < DDIM; k0 += 32) {
        gload_lds16(A + gA0 + k0, sA + c0 * 512);
        gload_lds16(A + gA1 + k0, sA + c1 * 512);
        gload_lds16(Bg + gB0 + k0, sG + c0 * 512);
        gload_lds16(Bg + gB1 + k0, sG + c1 * 512);
        gload_lds16(Bu + gB0 + k0, sU + c0 * 512);
        gload_lds16(Bu + gB1 + k0, sU + c1 * 512);
        asm volatile("s_waitcnt vmcnt(0)" ::: "memory");
        __syncthreads();

        s16x8 a[4], bg[4], bu[4];
#pragma unroll
        for (int mf = 0; mf < 4; ++mf)
            a[mf] = *(const s16x8*)&sA[(wr * 64 + mf * 16) * 32 + rA];
#pragma unroll
        for (int nf = 0; nf < 4; ++nf) {
            bg[nf] = *(const s16x8*)&sG[(wc * 64 + nf * 16) * 32 + rA];
            bu[nf] = *(const s16x8*)&sU[(wc * 64 + nf * 16) * 32 + rA];
        }
#pragma unroll
        for (int mf = 0; mf < 4; ++mf)
#pragma unroll
            for (int nf = 0; nf < 4; ++nf) {
                accG[mf][nf] = __builtin_amdgcn_mfma_f32_16x16x32_bf16(a[mf], bg[nf], accG[mf][nf], 0, 0, 0);
                accU[mf][nf] = __builtin_amdgcn_mfma_f32_16x16x32_bf16(a[mf], bu[nf], accU[mf][nf], 0, 0, 0);
            }
        __syncthreads();
    }

#pragma unroll
    for (int mf = 0; mf < 4; ++mf)
#pragma unroll
        for (int nf = 0; nf < 4; ++nf)
#pragma unroll
            for (int j = 0; j < 4; ++j) {
                int r = slot0 + wr * 64 + mf * 16 + (lane >> 4) * 4 + j;
                int c = colBase + wc * 64 + nf * 16 + (lane & 15);
                float g = accG[mf][nf][j], u = accU[mf][nf][j];
                float sg = 1.f / (1.f + __expf(-g));
                act[(size_t)r * INTER + c] = f2bf(g * sg * u);
            }
}

// ---------------- GEMM2 sparse: act @ wdT, scatter-accumulate ----------------
__global__ __launch_bounds__(256, 2) void gemm2_sparse(
    const unsigned short* __restrict__ A,
    const unsigned short* __restrict__ Bd,
    const int* __restrict__ tile_e,
    const int* __restrict__ tile_s0,
    const int* __restrict__ idx,
    const float* __restrict__ wslot,
    float* __restrict__ out) {
    const int lin = blockIdx.x;
    const int swz = (lin & 7) * (NWG2 / 8) + (lin >> 3);
    const int tileId = swz % CAP_TILES;
    const int colBase = (swz / CAP_TILES) * 128;
    int e = tile_e[tileId];
    if (e < 0) return;
    const int slot0 = tile_s0[tileId];
    Bd += (size_t)e * DDIM * INTER;

    __shared__ unsigned short sA[128 * 32];
    __shared__ unsigned short sB[128 * 32];
    const int tid = threadIdx.x, wid = tid >> 6, lane = tid & 63;
    const int wr = wid >> 1, wc = wid & 1;

    f32x4 acc[4][4];
#pragma unroll
    for (int i = 0; i < 4; ++i)
#pragma unroll
        for (int j = 0; j < 4; ++j) acc[i][j] = (f32x4)(0.f);

    const int c0 = wid, c1 = wid + 4;
    const int srow = lane >> 2;
    const int skoff = (lane & 3) * 8;
    const int rA = (lane & 15) * 32 + (lane >> 4) * 8;

    const size_t gA0 = (size_t)(slot0 + c0 * 16 + srow) * INTER + skoff;
    const size_t gA1 = (size_t)(slot0 + c1 * 16 + srow) * INTER + skoff;
    const size_t gB0 = (size_t)(colBase + c0 * 16 + srow) * INTER + skoff;
    const size_t gB1 = (size_t)(colBase + c1 * 16 + srow) * INTER + skoff;

    for (int k0 = 0; k0 < INTER; k0 += 32) {
        gload_lds16(A + gA0 + k0, sA + c0 * 512);
        gload_lds16(A + gA1 + k0, sA + c1 * 512);
        gload_lds16(Bd + gB0 + k0, sB + c0 * 512);
        gload_lds16(Bd + gB1 + k0, sB + c1 * 512);
        asm volatile("s_waitcnt vmcnt(0)" ::: "memory");
        __syncthreads();

        s16x8 a[4], b[4];
#pragma unroll
        for (int mf = 0; mf < 4; ++mf)
            a[mf] = *(const s16x8*)&sA[(wr * 64 + mf * 16) * 32 + rA];
#pragma unroll
        for (int nf = 0; nf < 4; ++nf)
            b[nf] = *(const s16x8*)&sB[(wc * 64 + nf * 16) * 32 + rA];
#pragma unroll
        for (int mf = 0; mf < 4; ++mf)
#pragma unroll
            for (int nf = 0; nf < 4; ++nf)
                acc[mf][nf] = __builtin_amdgcn_mfma_f32_16x16x32_bf16(a[mf], b[nf], acc[mf][nf], 0, 0, 0);
        __syncthreads();
    }

#pragma unroll
    for (int mf = 0; mf < 4; ++mf)
#pragma unroll
        for (int j = 0; j < 4; ++j) {
            int slot = slot0 + wr * 64 + mf * 16 + (lane >> 4) * 4 + j;
            int tok = idx[slot];
            float w = wslot[slot];
            if (w != 0.f) {
#pragma unroll
                for (int nf = 0; nf < 4; ++nf) {
                    int c = colBase + wc * 64 + nf * 16 + (lane & 15);
                    atomicAdd(&out[(size_t)tok * DDIM + c], acc[mf][nf][j] * w);
                }
            }
        }
}

// ---------------- host ----------------

extern "C" void kernel_launch(void* const* d_in, const int* in_sizes, int n_in,
                              void* d_out, int out_size, void* d_ws, size_t ws_size,
                              hipStream_t stream) {
    const float* h = (const float*)d_in[0];
    const float* gate_w = (const float*)d_in[1];
    const float* wg = (const float*)d_in[2];
    const float* wu = (const float*)d_in[3];
    const float* wd = (const float*)d_in[4];

    float* out = (float*)d_out;                       // results: 8192*1024
    float* lb = out + (size_t)B_TOK * DDIM;           // 1
    float* route = lb + 1;                            // 8192*8

    const size_t SZ_META = 1 << 20;                           // 1 MiB
    const size_t SZ_HB = (size_t)B_TOK * DDIM * 2;            // 16,777,216
    const size_t SZ_W = (size_t)NEXP * DDIM * INTER * 2;      // 46,137,344 per tensor
    const size_t SZ_ACT = (size_t)CAP_SLOTS * INTER * 2;      // 98,041,856
    const size_t NEED = SZ_META + SZ_HB + 2 * SZ_W + SZ_ACT;  // ~198.5 MiB
    if (ws_size < NEED) {
        fprintf(stderr, "kernel_launch: ws too small: %zu < %zu\n", ws_size, NEED);
        return;
    }
    char* ws = (char*)d_ws;
    // meta layout (within first 1 MiB)
    int* counts = (int*)(ws + 0);           // 8
    int* rank = (int*)(ws + 32);            // 8
    int* aoff = (int*)(ws + 64);            // 8
    int* tile_e = (int*)(ws + 128);         // 136
    int* tile_s0 = (int*)(ws + 1024);       // 136
    int* sel01 = (int*)(ws + 2048);         // 8192
    float2* wpair = (float2*)(ws + 34816);  // 8192
    int* idx = (int*)(ws + 100352);         // 17408
    float* wslot = (float*)(ws + 169984);   // 17408

    unsigned short* hb = (unsigned short*)(ws + SZ_META);
    unsigned short* wgT = (unsigned short*)(ws + SZ_META + SZ_HB);
    unsigned short* wuT = (unsigned short*)(ws + SZ_META + SZ_HB + SZ_W);
    unsigned short* act = (unsigned short*)(ws + SZ_META + SZ_HB + 2 * SZ_W);
    unsigned short* wdT = wgT;  // reuse wgT space AFTER gemm1 is done

    hipMemsetAsync(ws, 0, SZ_META, stream);
    hipMemsetAsync(out, 0, (size_t)B_TOK * DDIM * sizeof(float), stream);

    convert_f32_bf16<<<4096, 256, 0, stream>>>(h, hb, B_TOK * DDIM);
    transpose_convert_v2<<<dim3(INTER / 64, DDIM / 64, NEXP), 256, 0, stream>>>(wg, wgT, DDIM, INTER);
    transpose_convert_v2<<<dim3(INTER / 64, DDIM / 64, NEXP), 256, 0, stream>>>(wu, wuT, DDIM, INTER);

    gating_kernel<<<B_TOK / 4, 256, 0, stream>>>(h, gate_w, route, sel01, wpair, counts);
    setup_kernel<<<1, 256, 0, stream>>>(counts, aoff, tile_e, tile_s0);
    fill_kernel<<<B_TOK / 256, 256, 0, stream>>>(sel01, wpair, aoff, rank, idx, wslot);
    loss_kernel<<<1, 256, 0, stream>>>(route, lb);

    gemm1_sparse<<<NWG1, 256, 0, stream>>>(hb, wgT, wuT, tile_e, tile_s0, idx, act);

    // now wgT/wuT are dead: transpose wd into that space
    transpose_convert_v2<<<dim3(DDIM / 64, INTER / 64, NEXP), 256, 0, stream>>>(wd, wdT, INTER, DDIM);

    gemm2_sparse<<<NWG2, 256, 0, stream>>>(act, wdT, tile_e, tile_s0, idx, wslot, out);
}

// Round 4
// 805.913 us; speedup vs baseline: 2.2003x; 1.0416x over previous
//
#include <hip/hip_runtime.h>
#include <hip/hip_bf16.h>
#include <cstdio>

typedef short s16x8 __attribute__((ext_vector_type(8)));
typedef unsigned short u16x8 __attribute__((ext_vector_type(8)));
typedef float f32x4 __attribute__((ext_vector_type(4)));

#define B_TOK 8192      // b*l
#define DDIM 1024
#define INTER 2816
#define NEXP 8
#define CAP_TILES 136               // max sum ceil(cnt[e]/128) = 135; capacity 136
#define CAP_SLOTS (CAP_TILES * 128) // 17408

__device__ __forceinline__ unsigned short f2bf(float f) {
    unsigned int u = __float_as_uint(f);
    unsigned int r = u + 0x7fffu + ((u >> 16) & 1u);
    return (unsigned short)(r >> 16);
}

__device__ __forceinline__ void gload_lds16(const void* g, void* l) {
    __builtin_amdgcn_global_load_lds(
        (const __attribute__((address_space(1))) unsigned int*)g,
        (__attribute__((address_space(3))) unsigned int*)l, 16, 0, 0);
}

// ---------------- conversion kernels ----------------

__global__ void convert_f32_bf16(const float* __restrict__ src,
                                 unsigned short* __restrict__ dst, int n) {
    int i = (blockIdx.x * blockDim.x + threadIdx.x) * 8;
    if (i + 8 > n) return;
    float4 a = *(const float4*)(src + i);
    float4 b = *(const float4*)(src + i + 4);
    u16x8 o;
    o[0] = f2bf(a.x); o[1] = f2bf(a.y); o[2] = f2bf(a.z); o[3] = f2bf(a.w);
    o[4] = f2bf(b.x); o[5] = f2bf(b.y); o[6] = f2bf(b.z); o[7] = f2bf(b.w);
    *(u16x8*)(dst + i) = o;
}

// src: K x N f32 row-major (per expert via z), dst: N x K bf16. 64x64 tiles.
__global__ __launch_bounds__(256) void transpose_convert_v2(
    const float* __restrict__ src, unsigned short* __restrict__ dst,
    int K, int N) {
    __shared__ unsigned short tile[64][70];
    int e = blockIdx.z;
    src += (size_t)e * K * N;
    dst += (size_t)e * K * N;
    int n0 = blockIdx.x * 64, k0 = blockIdx.y * 64;
    int t = threadIdx.x;
    int lr = t >> 4;          // 0..15
    int lc = (t & 15) * 4;    // 0..60
#pragma unroll
    for (int p = 0; p < 4; ++p) {
        int kl = p * 16 + lr;
        float4 v = *(const float4*)(src + (size_t)(k0 + kl) * N + n0 + lc);
        tile[kl][lc + 0] = f2bf(v.x);
        tile[kl][lc + 1] = f2bf(v.y);
        tile[kl][lc + 2] = f2bf(v.z);
        tile[kl][lc + 3] = f2bf(v.w);
    }
    __syncthreads();
    int sn = t >> 3;          // 0..31
    int sk = (t & 7) * 8;     // 0..56
#pragma unroll
    for (int p = 0; p < 2; ++p) {
        int nl = p * 32 + sn;
        u16x8 o;
#pragma unroll
        for (int j = 0; j < 8; ++j) o[j] = tile[sk + j][nl];
        *(u16x8*)(dst + (size_t)(n0 + nl) * K + k0 + sk) = o;
    }
}

// ---------------- gating ----------------
__global__ void gating_kernel(const float* __restrict__ h,
                              const float* __restrict__ gw,
                              float* __restrict__ route,
                              int* __restrict__ sel01,
                              float2* __restrict__ wpair,
                              int* __restrict__ counts) {
    int wid = threadIdx.x >> 6, lane = threadIdx.x & 63;
    int t = blockIdx.x * 4 + wid;
    if (t >= B_TOK) return;
    const float* hp = h + (size_t)t * DDIM + lane * 16;
    const float* gp = gw + (size_t)lane * 16 * NEXP;
    float s[8] = {0, 0, 0, 0, 0, 0, 0, 0};
#pragma unroll
    for (int kk = 0; kk < 16; ++kk) {
        float hv = hp[kk];
#pragma unroll
        for (int e = 0; e < 8; ++e) s[e] += hv * gp[kk * 8 + e];
    }
#pragma unroll
    for (int off = 32; off > 0; off >>= 1) {
#pragma unroll
        for (int e = 0; e < 8; ++e) s[e] += __shfl_down(s[e], off);
    }
    if (lane == 0) {
        float m0 = -1e30f; int i0 = 0;
#pragma unroll
        for (int e = 0; e < 8; ++e) if (s[e] > m0) { m0 = s[e]; i0 = e; }
        float m1 = -1e30f; int i1 = -1;
#pragma unroll
        for (int e = 0; e < 8; ++e) if (e != i0 && s[e] > m1) { m1 = s[e]; i1 = e; }
        float d = __expf(m1 - m0);
        float w0 = 1.f / (1.f + d);
        float w1 = d * w0;
#pragma unroll
        for (int e = 0; e < 8; ++e)
            route[(size_t)t * 8 + e] = (e == i0) ? w0 : ((e == i1) ? w1 : 0.f);
        sel01[t] = i0 | (i1 << 8);
        wpair[t] = make_float2(w0, w1);
        atomicAdd(&counts[i0], 1);
        atomicAdd(&counts[i1], 1);
    }
}

// single block: per-expert 128-aligned slot offsets + tile -> (expert, slot0) table
__global__ void setup_kernel(const int* __restrict__ counts,
                             int* __restrict__ aoff,
                             int* __restrict__ tile_e,
                             int* __restrict__ tile_s0) {
    __shared__ int s_aoff[8], s_t0[9];
    if (threadIdx.x == 0) {
        int acc_slot = 0, acc_tile = 0;
        for (int e = 0; e < 8; ++e) {
            s_aoff[e] = acc_slot;
            s_t0[e] = acc_tile;
            int nt = (counts[e] + 127) >> 7;
            acc_slot += nt << 7;
            acc_tile += nt;
        }
        s_t0[8] = acc_tile;
        for (int e = 0; e < 8; ++e) aoff[e] = s_aoff[e];
    }
    __syncthreads();
    int t = threadIdx.x;
    if (t < CAP_TILES) {
        int e = -1, s0 = 0;
        for (int x = 0; x < 8; ++x)
            if (t >= s_t0[x] && t < s_t0[x + 1]) { e = x; s0 = s_aoff[x] + ((t - s_t0[x]) << 7); }
        tile_e[t] = e;
        tile_s0[t] = s0;
    }
}

__global__ void fill_kernel(const int* __restrict__ sel01,
                            const float2* __restrict__ wpair,
                            const int* __restrict__ aoff,
                            int* __restrict__ rank,
                            int* __restrict__ idx,
                            int2* __restrict__ tslot) {
    int t = blockIdx.x * 256 + threadIdx.x;
    if (t >= B_TOK) return;
    int s = sel01[t];
    int e0 = s & 0xff, e1 = (s >> 8) & 0xff;
    int p0 = atomicAdd(&rank[e0], 1);
    int sl0 = aoff[e0] + p0;
    idx[sl0] = t;
    int p1 = atomicAdd(&rank[e1], 1);
    int sl1 = aoff[e1] + p1;
    idx[sl1] = t;
    tslot[t] = make_int2(sl0, sl1);
}

__global__ void loss_kernel(const float* __restrict__ route, float* __restrict__ lb) {
    __shared__ float ps[8];
    int tid = threadIdx.x;
    if (tid < 8) ps[tid] = 0.f;
    __syncthreads();
    float s[8] = {0, 0, 0, 0, 0, 0, 0, 0};
    for (int t = tid; t < B_TOK; t += 256) {
        const float* rp = route + (size_t)t * 8;
#pragma unroll
        for (int e = 0; e < 8; ++e) s[e] += rp[e];
    }
#pragma unroll
    for (int e = 0; e < 8; ++e) atomicAdd(&ps[e], s[e]);
    __syncthreads();
    if (tid == 0) {
        float acc = 0.f;
#pragma unroll
        for (int e = 0; e < 8; ++e) {
            float p = ps[e] / (float)B_TOK;
            acc += p * p;
        }
        lb[0] = 0.01f * acc;
    }
}

// ---------------- GEMM1 sparse: gathered rows, g/u dual, fused silu ----------------
__global__ __launch_bounds__(256, 2) void gemm1_sparse(
    const unsigned short* __restrict__ A,
    const unsigned short* __restrict__ Bg,
    const unsigned short* __restrict__ Bu,
    const int* __restrict__ tile_e,
    const int* __restrict__ tile_s0,
    const int* __restrict__ idx,
    unsigned short* __restrict__ act) {
    int e = tile_e[blockIdx.x];
    if (e < 0) return;
    const int slot0 = tile_s0[blockIdx.x];
    Bg += (size_t)e * DDIM * INTER;
    Bu += (size_t)e * DDIM * INTER;

    __shared__ unsigned short sA[128 * 32];
    __shared__ unsigned short sG[128 * 32];
    __shared__ unsigned short sU[128 * 32];
    const int tid = threadIdx.x, wid = tid >> 6, lane = tid & 63;
    const int wr = wid >> 1, wc = wid & 1;
    const int colBase = blockIdx.y * 128;

    f32x4 accG[4][4], accU[4][4];
#pragma unroll
    for (int i = 0; i < 4; ++i)
#pragma unroll
        for (int j = 0; j < 4; ++j) { accG[i][j] = (f32x4)(0.f); accU[i][j] = (f32x4)(0.f); }

    const int c0 = wid, c1 = wid + 4;
    const int srow = lane >> 2;
    const int skoff = (lane & 3) * 8;
    const int rA = (lane & 15) * 32 + (lane >> 4) * 8;

    const size_t gA0 = (size_t)idx[slot0 + c0 * 16 + srow] * DDIM + skoff;
    const size_t gA1 = (size_t)idx[slot0 + c1 * 16 + srow] * DDIM + skoff;
    const size_t gB0 = (size_t)(colBase + c0 * 16 + srow) * DDIM + skoff;
    const size_t gB1 = (size_t)(colBase + c1 * 16 + srow) * DDIM + skoff;

    for (int k0 = 0; k0 < DDIM; k0 += 32) {
        gload_lds16(A + gA0 + k0, sA + c0 * 512);
        gload_lds16(A + gA1 + k0, sA + c1 * 512);
        gload_lds16(Bg + gB0 + k0, sG + c0 * 512);
        gload_lds16(Bg + gB1 + k0, sG + c1 * 512);
        gload_lds16(Bu + gB0 + k0, sU + c0 * 512);
        gload_lds16(Bu + gB1 + k0, sU + c1 * 512);
        asm volatile("s_waitcnt vmcnt(0)" ::: "memory");
        __syncthreads();

        s16x8 a[4], bg[4], bu[4];
#pragma unroll
        for (int mf = 0; mf < 4; ++mf)
            a[mf] = *(const s16x8*)&sA[(wr * 64 + mf * 16) * 32 + rA];
#pragma unroll
        for (int nf = 0; nf < 4; ++nf) {
            bg[nf] = *(const s16x8*)&sG[(wc * 64 + nf * 16) * 32 + rA];
            bu[nf] = *(const s16x8*)&sU[(wc * 64 + nf * 16) * 32 + rA];
        }
#pragma unroll
        for (int mf = 0; mf < 4; ++mf)
#pragma unroll
            for (int nf = 0; nf < 4; ++nf) {
                accG[mf][nf] = __builtin_amdgcn_mfma_f32_16x16x32_bf16(a[mf], bg[nf], accG[mf][nf], 0, 0, 0);
                accU[mf][nf] = __builtin_amdgcn_mfma_f32_16x16x32_bf16(a[mf], bu[nf], accU[mf][nf], 0, 0, 0);
            }
        __syncthreads();
    }

#pragma unroll
    for (int mf = 0; mf < 4; ++mf)
#pragma unroll
        for (int nf = 0; nf < 4; ++nf)
#pragma unroll
            for (int j = 0; j < 4; ++j) {
                int r = slot0 + wr * 64 + mf * 16 + (lane >> 4) * 4 + j;
                int c = colBase + wc * 64 + nf * 16 + (lane & 15);
                float g = accG[mf][nf][j], u = accU[mf][nf][j];
                float sg = 1.f / (1.f + __expf(-g));
                act[(size_t)r * INTER + c] = f2bf(g * sg * u);
            }
}

// ---------------- GEMM2 v2: act @ wdT over an N-half, slot-major f32 output ----------------
// A: act [CAP_SLOTS][2816] bf16, B: wdT [E][1024][2816] bf16,
// y: [CAP_SLOTS][512] f32 (plain stores, no atomics). colHalfBase in {0, 512}.
__global__ __launch_bounds__(256, 3) void gemm2_sparse_v2(
    const unsigned short* __restrict__ A,
    const unsigned short* __restrict__ Bd,
    const int* __restrict__ tile_e,
    const int* __restrict__ tile_s0,
    float* __restrict__ y,
    int colHalfBase) {
    int e = tile_e[blockIdx.x];
    if (e < 0) return;
    const int slot0 = tile_s0[blockIdx.x];
    const int colLocal = blockIdx.y * 128;           // within the 512-wide half
    const int colBase = colHalfBase + colLocal;      // row index into wdT
    Bd += (size_t)e * DDIM * INTER;

    __shared__ unsigned short sA[128 * 32];
    __shared__ unsigned short sB[128 * 32];
    const int tid = threadIdx.x, wid = tid >> 6, lane = tid & 63;
    const int wr = wid >> 1, wc = wid & 1;

    f32x4 acc[4][4];
#pragma unroll
    for (int i = 0; i < 4; ++i)
#pragma unroll
        for (int j = 0; j < 4; ++j) acc[i][j] = (f32x4)(0.f);

    const int c0 = wid, c1 = wid + 4;
    const int srow = lane >> 2;
    const int skoff = (lane & 3) * 8;
    const int rA = (lane & 15) * 32 + (lane >> 4) * 8;

    const size_t gA0 = (size_t)(slot0 + c0 * 16 + srow) * INTER + skoff;
    const size_t gA1 = (size_t)(slot0 + c1 * 16 + srow) * INTER + skoff;
    const size_t gB0 = (size_t)(colBase + c0 * 16 + srow) * INTER + skoff;
    const size_t gB1 = (size_t)(colBase + c1 * 16 + srow) * INTER + skoff;

    for (int k0 = 0; k0 < INTER; k0 += 32) {
        gload_lds16(A + gA0 + k0, sA + c0 * 512);
        gload_lds16(A + gA1 + k0, sA + c1 * 512);
        gload_lds16(Bd + gB0 + k0, sB + c0 * 512);
        gload_lds16(Bd + gB1 + k0, sB + c1 * 512);
        asm volatile("s_waitcnt vmcnt(0)" ::: "memory");
        __syncthreads();

        s16x8 a[4], b[4];
#pragma unroll
        for (int mf = 0; mf < 4; ++mf)
            a[mf] = *(const s16x8*)&sA[(wr * 64 + mf * 16) * 32 + rA];
#pragma unroll
        for (int nf = 0; nf < 4; ++nf)
            b[nf] = *(const s16x8*)&sB[(wc * 64 + nf * 16) * 32 + rA];
#pragma unroll
        for (int mf = 0; mf < 4; ++mf)
#pragma unroll
            for (int nf = 0; nf < 4; ++nf)
                acc[mf][nf] = __builtin_amdgcn_mfma_f32_16x16x32_bf16(a[mf], b[nf], acc[mf][nf], 0, 0, 0);
        __syncthreads();
    }

#pragma unroll
    for (int mf = 0; mf < 4; ++mf)
#pragma unroll
        for (int j = 0; j < 4; ++j) {
            int slot = slot0 + wr * 64 + mf * 16 + (lane >> 4) * 4 + j;
#pragma unroll
            for (int nf = 0; nf < 4; ++nf) {
                int cl = colLocal + wc * 64 + nf * 16 + (lane & 15);
                y[(size_t)slot * 512 + cl] = acc[mf][nf][j];
            }
        }
}

// out[t][colHalfBase + c] = w0 * y[sl0][c] + w1 * y[sl1][c], float4-vectorized
__global__ __launch_bounds__(256) void combine_kernel(
    const float* __restrict__ y,
    const int2* __restrict__ tslot,
    const float2* __restrict__ wpair,
    float* __restrict__ out,
    int colHalfBase) {
    int gid = blockIdx.x * 256 + threadIdx.x;  // 0 .. 8192*128-1
    int tok = gid >> 7;
    int c4 = gid & 127;
    int2 ts = tslot[tok];
    float2 w = wpair[tok];
    const float4* y4 = (const float4*)y;
    float4 a = y4[(size_t)ts.x * 128 + c4];
    float4 b = y4[(size_t)ts.y * 128 + c4];
    float4 r;
    r.x = w.x * a.x + w.y * b.x;
    r.y = w.x * a.y + w.y * b.y;
    r.z = w.x * a.z + w.y * b.z;
    r.w = w.x * a.w + w.y * b.w;
    *(float4*)(out + (size_t)tok * DDIM + colHalfBase + c4 * 4) = r;
}

// ---------------- host ----------------

extern "C" void kernel_launch(void* const* d_in, const int* in_sizes, int n_in,
                              void* d_out, int out_size, void* d_ws, size_t ws_size,
                              hipStream_t stream) {
    const float* h = (const float*)d_in[0];
    const float* gate_w = (const float*)d_in[1];
    const float* wg = (const float*)d_in[2];
    const float* wu = (const float*)d_in[3];
    const float* wd = (const float*)d_in[4];

    float* out = (float*)d_out;                       // results: 8192*1024
    float* lb = out + (size_t)B_TOK * DDIM;           // 1
    float* route = lb + 1;                            // 8192*8

    const size_t SZ_META = 1 << 20;                           // 1 MiB
    const size_t SZ_HB = (size_t)B_TOK * DDIM * 2;            // 16,777,216
    const size_t SZ_W = (size_t)NEXP * DDIM * INTER * 2;      // 46,137,344 per tensor
    const size_t SZ_ACT = (size_t)CAP_SLOTS * INTER * 2;      // 98,041,856
    const size_t NEED = SZ_META + SZ_HB + 2 * SZ_W + SZ_ACT;  // ~198.5 MiB
    if (ws_size < NEED) {
        fprintf(stderr, "kernel_launch: ws too small: %zu < %zu\n", ws_size, NEED);
        return;
    }
    char* ws = (char*)d_ws;
    // meta layout (within first 1 MiB)
    int* counts = (int*)(ws + 0);            // 8
    int* rank = (int*)(ws + 32);             // 8
    int* aoff = (int*)(ws + 64);             // 8
    int* tile_e = (int*)(ws + 128);          // 136
    int* tile_s0 = (int*)(ws + 1024);        // 136
    int* sel01 = (int*)(ws + 2048);          // 8192
    float2* wpair = (float2*)(ws + 34816);   // 8192
    int* idx = (int*)(ws + 100352);          // 17408
    int2* tslot = (int2*)(ws + 262144);      // 8192 int2 = 64KB

    unsigned short* hb = (unsigned short*)(ws + SZ_META);
    unsigned short* wgT = (unsigned short*)(ws + SZ_META + SZ_HB);
    unsigned short* wuT = (unsigned short*)(ws + SZ_META + SZ_HB + SZ_W);
    unsigned short* act = (unsigned short*)(ws + SZ_META + SZ_HB + 2 * SZ_W);
    unsigned short* wdT = wgT;                          // reuse wgT space AFTER gemm1
    float* y = (float*)(ws + SZ_META + SZ_HB + SZ_W);   // reuse wuT space AFTER gemm1 (35.6MB < 46.1MB)

    hipMemsetAsync(ws, 0, SZ_META, stream);

    convert_f32_bf16<<<4096, 256, 0, stream>>>(h, hb, B_TOK * DDIM);
    transpose_convert_v2<<<dim3(INTER / 64, DDIM / 64, NEXP), 256, 0, stream>>>(wg, wgT, DDIM, INTER);
    transpose_convert_v2<<<dim3(INTER / 64, DDIM / 64, NEXP), 256, 0, stream>>>(wu, wuT, DDIM, INTER);

    gating_kernel<<<B_TOK / 4, 256, 0, stream>>>(h, gate_w, route, sel01, wpair, counts);
    setup_kernel<<<1, 256, 0, stream>>>(counts, aoff, tile_e, tile_s0);
    fill_kernel<<<B_TOK / 256, 256, 0, stream>>>(sel01, wpair, aoff, rank, idx, tslot);
    loss_kernel<<<1, 256, 0, stream>>>(route, lb);

    gemm1_sparse<<<dim3(CAP_TILES, INTER / 128), 256, 0, stream>>>(
        hb, wgT, wuT, tile_e, tile_s0, idx, act);

    // now wgT/wuT are dead: transpose wd into wgT's space; y reuses wuT's space
    transpose_convert_v2<<<dim3(DDIM / 64, INTER / 64, NEXP), 256, 0, stream>>>(wd, wdT, INTER, DDIM);

    for (int half = 0; half < 2; ++half) {
        gemm2_sparse_v2<<<dim3(CAP_TILES, 4), 256, 0, stream>>>(
            act, wdT, tile_e, tile_s0, y, half * 512);
        combine_kernel<<<(B_TOK * 128) / 256, 256, 0, stream>>>(
            y, tslot, wpair, out, half * 512);
    }
}

// Round 5
// 797.718 us; speedup vs baseline: 2.2229x; 1.0103x over previous
//
#include <hip/hip_runtime.h>
#include <hip/hip_bf16.h>
#include <cstdio>

typedef short s16x8 __attribute__((ext_vector_type(8)));
typedef unsigned short u16x8 __attribute__((ext_vector_type(8)));
typedef float f32x4 __attribute__((ext_vector_type(4)));

#define B_TOK 8192      // b*l
#define DDIM 1024
#define INTER 2816
#define NEXP 8
#define CAP_TILES 136               // max sum ceil(cnt[e]/128) = 135; capacity 136
#define CAP_SLOTS (CAP_TILES * 128) // 17408

__device__ __forceinline__ unsigned short f2bf(float f) {
    unsigned int u = __float_as_uint(f);
    unsigned int r = u + 0x7fffu + ((u >> 16) & 1u);
    return (unsigned short)(r >> 16);
}

__device__ __forceinline__ float bf2f(unsigned short u) {
    unsigned int x = ((unsigned int)u) << 16;
    return __uint_as_float(x);
}

__device__ __forceinline__ void gload_lds16(const void* g, void* l) {
    __builtin_amdgcn_global_load_lds(
        (const __attribute__((address_space(1))) unsigned int*)g,
        (__attribute__((address_space(3))) unsigned int*)l, 16, 0, 0);
}

// ---------------- transpose+convert ----------------
// src: K x N f32 row-major (per expert via z), dst: N x K bf16. 64x64 tiles.
__global__ __launch_bounds__(256) void transpose_convert_v2(
    const float* __restrict__ src, unsigned short* __restrict__ dst,
    int K, int N) {
    __shared__ unsigned short tile[64][70];
    int e = blockIdx.z;
    src += (size_t)e * K * N;
    dst += (size_t)e * K * N;
    int n0 = blockIdx.x * 64, k0 = blockIdx.y * 64;
    int t = threadIdx.x;
    int lr = t >> 4;          // 0..15
    int lc = (t & 15) * 4;    // 0..60
#pragma unroll
    for (int p = 0; p < 4; ++p) {
        int kl = p * 16 + lr;
        float4 v = *(const float4*)(src + (size_t)(k0 + kl) * N + n0 + lc);
        tile[kl][lc + 0] = f2bf(v.x);
        tile[kl][lc + 1] = f2bf(v.y);
        tile[kl][lc + 2] = f2bf(v.z);
        tile[kl][lc + 3] = f2bf(v.w);
    }
    __syncthreads();
    int sn = t >> 3;          // 0..31
    int sk = (t & 7) * 8;     // 0..56
#pragma unroll
    for (int p = 0; p < 2; ++p) {
        int nl = p * 32 + sn;
        u16x8 o;
#pragma unroll
        for (int j = 0; j < 8; ++j) o[j] = tile[sk + j][nl];
        *(u16x8*)(dst + (size_t)(n0 + nl) * K + k0 + sk) = o;
    }
}

// ---------------- gating (fused: bf16-convert of h, routing, loss sums) -------
// one wave per token; exact fp32 logits, top-2 (lowest index wins ties), softmax
__global__ void gating_kernel(const float* __restrict__ h,
                              const float* __restrict__ gw,
                              float* __restrict__ route,
                              int* __restrict__ sel01,
                              float2* __restrict__ wpair,
                              int* __restrict__ counts,
                              float* __restrict__ sums,
                              unsigned short* __restrict__ hb) {
    int wid = threadIdx.x >> 6, lane = threadIdx.x & 63;
    int t = blockIdx.x * 4 + wid;
    const float* hp = h + (size_t)t * DDIM + lane * 16;
    float4 hv[4];
#pragma unroll
    for (int p = 0; p < 4; ++p) hv[p] = ((const float4*)hp)[p];

    // side product: bf16 h
    u16x8 o0, o1;
    o0[0] = f2bf(hv[0].x); o0[1] = f2bf(hv[0].y); o0[2] = f2bf(hv[0].z); o0[3] = f2bf(hv[0].w);
    o0[4] = f2bf(hv[1].x); o0[5] = f2bf(hv[1].y); o0[6] = f2bf(hv[1].z); o0[7] = f2bf(hv[1].w);
    o1[0] = f2bf(hv[2].x); o1[1] = f2bf(hv[2].y); o1[2] = f2bf(hv[2].z); o1[3] = f2bf(hv[2].w);
    o1[4] = f2bf(hv[3].x); o1[5] = f2bf(hv[3].y); o1[6] = f2bf(hv[3].z); o1[7] = f2bf(hv[3].w);
    unsigned short* hbp = hb + (size_t)t * DDIM + lane * 16;
    *(u16x8*)hbp = o0;
    *(u16x8*)(hbp + 8) = o1;

    const float4* gp4 = (const float4*)(gw + (size_t)lane * 16 * NEXP);
    float s[8] = {0, 0, 0, 0, 0, 0, 0, 0};
#pragma unroll
    for (int p = 0; p < 4; ++p) {
#pragma unroll
        for (int q = 0; q < 4; ++q) {
            int kk = p * 4 + q;
            float hvk = (q == 0) ? hv[p].x : (q == 1) ? hv[p].y : (q == 2) ? hv[p].z : hv[p].w;
            float4 a = gp4[kk * 2], b = gp4[kk * 2 + 1];
            s[0] += hvk * a.x; s[1] += hvk * a.y; s[2] += hvk * a.z; s[3] += hvk * a.w;
            s[4] += hvk * b.x; s[5] += hvk * b.y; s[6] += hvk * b.z; s[7] += hvk * b.w;
        }
    }
#pragma unroll
    for (int off = 32; off > 0; off >>= 1) {
#pragma unroll
        for (int e = 0; e < 8; ++e) s[e] += __shfl_down(s[e], off);
    }
    if (lane == 0) {
        float m0 = -1e30f; int i0 = 0;
#pragma unroll
        for (int e = 0; e < 8; ++e) if (s[e] > m0) { m0 = s[e]; i0 = e; }
        float m1 = -1e30f; int i1 = -1;
#pragma unroll
        for (int e = 0; e < 8; ++e) if (e != i0 && s[e] > m1) { m1 = s[e]; i1 = e; }
        float d = __expf(m1 - m0);
        float w0 = 1.f / (1.f + d);
        float w1 = d * w0;
#pragma unroll
        for (int e = 0; e < 8; ++e)
            route[(size_t)t * 8 + e] = (e == i0) ? w0 : ((e == i1) ? w1 : 0.f);
        sel01[t] = i0 | (i1 << 8);
        wpair[t] = make_float2(w0, w1);
        atomicAdd(&counts[i0], 1);
        atomicAdd(&counts[i1], 1);
        atomicAdd(&sums[i0], w0);
        atomicAdd(&sums[i1], w1);
    }
}

// single block: per-expert 128-aligned slot offsets + tile table + lb_loss finalize
__global__ void setup_kernel(const int* __restrict__ counts,
                             const float* __restrict__ sums,
                             int* __restrict__ aoff,
                             int* __restrict__ tile_e,
                             int* __restrict__ tile_s0,
                             float* __restrict__ lb) {
    __shared__ int s_aoff[8], s_t0[9];
    if (threadIdx.x == 0) {
        int acc_slot = 0, acc_tile = 0;
        for (int e = 0; e < 8; ++e) {
            s_aoff[e] = acc_slot;
            s_t0[e] = acc_tile;
            int nt = (counts[e] + 127) >> 7;
            acc_slot += nt << 7;
            acc_tile += nt;
        }
        s_t0[8] = acc_tile;
        for (int e = 0; e < 8; ++e) aoff[e] = s_aoff[e];
        float acc = 0.f;
        for (int e = 0; e < 8; ++e) {
            float p = sums[e] / (float)B_TOK;
            acc += p * p;
        }
        lb[0] = 0.01f * acc;
    }
    __syncthreads();
    int t = threadIdx.x;
    if (t < CAP_TILES) {
        int e = -1, s0 = 0;
        for (int x = 0; x < 8; ++x)
            if (t >= s_t0[x] && t < s_t0[x + 1]) { e = x; s0 = s_aoff[x] + ((t - s_t0[x]) << 7); }
        tile_e[t] = e;
        tile_s0[t] = s0;
    }
}

__global__ void fill_kernel(const int* __restrict__ sel01,
                            const int* __restrict__ aoff,
                            int* __restrict__ rank,
                            int* __restrict__ idx,
                            int2* __restrict__ tslot) {
    int t = blockIdx.x * 256 + threadIdx.x;
    if (t >= B_TOK) return;
    int s = sel01[t];
    int e0 = s & 0xff, e1 = (s >> 8) & 0xff;
    int p0 = atomicAdd(&rank[e0], 1);
    int sl0 = aoff[e0] + p0;
    idx[sl0] = t;
    int p1 = atomicAdd(&rank[e1], 1);
    int sl1 = aoff[e1] + p1;
    idx[sl1] = t;
    tslot[t] = make_int2(sl0, sl1);
}

// ---------------- GEMM1 sparse: gathered rows, g/u dual, fused silu ----------------
__global__ __launch_bounds__(256, 2) void gemm1_sparse(
    const unsigned short* __restrict__ A,
    const unsigned short* __restrict__ Bg,
    const unsigned short* __restrict__ Bu,
    const int* __restrict__ tile_e,
    const int* __restrict__ tile_s0,
    const int* __restrict__ idx,
    unsigned short* __restrict__ act) {
    int e = tile_e[blockIdx.x];
    if (e < 0) return;
    const int slot0 = tile_s0[blockIdx.x];
    Bg += (size_t)e * DDIM * INTER;
    Bu += (size_t)e * DDIM * INTER;

    __shared__ unsigned short sA[128 * 32];
    __shared__ unsigned short sG[128 * 32];
    __shared__ unsigned short sU[128 * 32];
    const int tid = threadIdx.x, wid = tid >> 6, lane = tid & 63;
    const int wr = wid >> 1, wc = wid & 1;
    const int colBase = blockIdx.y * 128;

    f32x4 accG[4][4], accU[4][4];
#pragma unroll
    for (int i = 0; i < 4; ++i)
#pragma unroll
        for (int j = 0; j < 4; ++j) { accG[i][j] = (f32x4)(0.f); accU[i][j] = (f32x4)(0.f); }

    const int c0 = wid, c1 = wid + 4;
    const int srow = lane >> 2;
    const int skoff = (lane & 3) * 8;
    const int rA = (lane & 15) * 32 + (lane >> 4) * 8;

    const size_t gA0 = (size_t)idx[slot0 + c0 * 16 + srow] * DDIM + skoff;
    const size_t gA1 = (size_t)idx[slot0 + c1 * 16 + srow] * DDIM + skoff;
    const size_t gB0 = (size_t)(colBase + c0 * 16 + srow) * DDIM + skoff;
    const size_t gB1 = (size_t)(colBase + c1 * 16 + srow) * DDIM + skoff;

    for (int k0 = 0; k0 < DDIM; k0 += 32) {
        gload_lds16(A + gA0 + k0, sA + c0 * 512);
        gload_lds16(A + gA1 + k0, sA + c1 * 512);
        gload_lds16(Bg + gB0 + k0, sG + c0 * 512);
        gload_lds16(Bg + gB1 + k0, sG + c1 * 512);
        gload_lds16(Bu + gB0 + k0, sU + c0 * 512);
        gload_lds16(Bu + gB1 + k0, sU + c1 * 512);
        asm volatile("s_waitcnt vmcnt(0)" ::: "memory");
        __syncthreads();

        s16x8 a[4], bg[4], bu[4];
#pragma unroll
        for (int mf = 0; mf < 4; ++mf)
            a[mf] = *(const s16x8*)&sA[(wr * 64 + mf * 16) * 32 + rA];
#pragma unroll
        for (int nf = 0; nf < 4; ++nf) {
            bg[nf] = *(const s16x8*)&sG[(wc * 64 + nf * 16) * 32 + rA];
            bu[nf] = *(const s16x8*)&sU[(wc * 64 + nf * 16) * 32 + rA];
        }
#pragma unroll
        for (int mf = 0; mf < 4; ++mf)
#pragma unroll
            for (int nf = 0; nf < 4; ++nf) {
                accG[mf][nf] = __builtin_amdgcn_mfma_f32_16x16x32_bf16(a[mf], bg[nf], accG[mf][nf], 0, 0, 0);
                accU[mf][nf] = __builtin_amdgcn_mfma_f32_16x16x32_bf16(a[mf], bu[nf], accU[mf][nf], 0, 0, 0);
            }
        __syncthreads();
    }

#pragma unroll
    for (int mf = 0; mf < 4; ++mf)
#pragma unroll
        for (int nf = 0; nf < 4; ++nf)
#pragma unroll
            for (int j = 0; j < 4; ++j) {
                int r = slot0 + wr * 64 + mf * 16 + (lane >> 4) * 4 + j;
                int c = colBase + wc * 64 + nf * 16 + (lane & 15);
                float g = accG[mf][nf][j], u = accU[mf][nf][j];
                float sg = 1.f / (1.f + __expf(-g));
                act[(size_t)r * INTER + c] = f2bf(g * sg * u);
            }
}

// ---------------- GEMM2 v3: act @ wdT full-width, slot-major bf16 output ----------------
// A: act [CAP_SLOTS][2816] bf16, B: wdT [E][1024][2816] bf16, y: [CAP_SLOTS][1024] bf16
__global__ __launch_bounds__(256, 3) void gemm2_sparse_v3(
    const unsigned short* __restrict__ A,
    const unsigned short* __restrict__ Bd,
    const int* __restrict__ tile_e,
    const int* __restrict__ tile_s0,
    unsigned short* __restrict__ y) {
    int e = tile_e[blockIdx.x];
    if (e < 0) return;
    const int slot0 = tile_s0[blockIdx.x];
    const int colBase = blockIdx.y * 128;
    Bd += (size_t)e * DDIM * INTER;

    __shared__ unsigned short sA[128 * 32];
    __shared__ unsigned short sB[128 * 32];
    const int tid = threadIdx.x, wid = tid >> 6, lane = tid & 63;
    const int wr = wid >> 1, wc = wid & 1;

    f32x4 acc[4][4];
#pragma unroll
    for (int i = 0; i < 4; ++i)
#pragma unroll
        for (int j = 0; j < 4; ++j) acc[i][j] = (f32x4)(0.f);

    const int c0 = wid, c1 = wid + 4;
    const int srow = lane >> 2;
    const int skoff = (lane & 3) * 8;
    const int rA = (lane & 15) * 32 + (lane >> 4) * 8;

    const size_t gA0 = (size_t)(slot0 + c0 * 16 + srow) * INTER + skoff;
    const size_t gA1 = (size_t)(slot0 + c1 * 16 + srow) * INTER + skoff;
    const size_t gB0 = (size_t)(colBase + c0 * 16 + srow) * INTER + skoff;
    const size_t gB1 = (size_t)(colBase + c1 * 16 + srow) * INTER + skoff;

    for (int k0 = 0; k0 < INTER; k0 += 32) {
        gload_lds16(A + gA0 + k0, sA + c0 * 512);
        gload_lds16(A + gA1 + k0, sA + c1 * 512);
        gload_lds16(Bd + gB0 + k0, sB + c0 * 512);
        gload_lds16(Bd + gB1 + k0, sB + c1 * 512);
        asm volatile("s_waitcnt vmcnt(0)" ::: "memory");
        __syncthreads();

        s16x8 a[4], b[4];
#pragma unroll
        for (int mf = 0; mf < 4; ++mf)
            a[mf] = *(const s16x8*)&sA[(wr * 64 + mf * 16) * 32 + rA];
#pragma unroll
        for (int nf = 0; nf < 4; ++nf)
            b[nf] = *(const s16x8*)&sB[(wc * 64 + nf * 16) * 32 + rA];
#pragma unroll
        for (int mf = 0; mf < 4; ++mf)
#pragma unroll
            for (int nf = 0; nf < 4; ++nf)
                acc[mf][nf] = __builtin_amdgcn_mfma_f32_16x16x32_bf16(a[mf], b[nf], acc[mf][nf], 0, 0, 0);
        __syncthreads();
    }

#pragma unroll
    for (int mf = 0; mf < 4; ++mf)
#pragma unroll
        for (int j = 0; j < 4; ++j) {
            int slot = slot0 + wr * 64 + mf * 16 + (lane >> 4) * 4 + j;
#pragma unroll
            for (int nf = 0; nf < 4; ++nf) {
                int c = colBase + wc * 64 + nf * 16 + (lane & 15);
                y[(size_t)slot * DDIM + c] = f2bf(acc[mf][nf][j]);
            }
        }
}

// out[t][c] = w0 * y[sl0][c] + w1 * y[sl1][c]; y is bf16, out f32
__global__ __launch_bounds__(256) void combine_kernel(
    const unsigned short* __restrict__ y,
    const int2* __restrict__ tslot,
    const float2* __restrict__ wpair,
    float* __restrict__ out) {
    int gid = blockIdx.x * 256 + threadIdx.x;  // 0 .. 8192*128-1
    int tok = gid >> 7;
    int c8 = (gid & 127) * 8;
    int2 ts = tslot[tok];
    float2 w = wpair[tok];
    u16x8 a = *(const u16x8*)(y + (size_t)ts.x * DDIM + c8);
    u16x8 b = *(const u16x8*)(y + (size_t)ts.y * DDIM + c8);
    float4 r0, r1;
    r0.x = w.x * bf2f(a[0]) + w.y * bf2f(b[0]);
    r0.y = w.x * bf2f(a[1]) + w.y * bf2f(b[1]);
    r0.z = w.x * bf2f(a[2]) + w.y * bf2f(b[2]);
    r0.w = w.x * bf2f(a[3]) + w.y * bf2f(b[3]);
    r1.x = w.x * bf2f(a[4]) + w.y * bf2f(b[4]);
    r1.y = w.x * bf2f(a[5]) + w.y * bf2f(b[5]);
    r1.z = w.x * bf2f(a[6]) + w.y * bf2f(b[6]);
    r1.w = w.x * bf2f(a[7]) + w.y * bf2f(b[7]);
    float* op = out + (size_t)tok * DDIM + c8;
    *(float4*)op = r0;
    *(float4*)(op + 4) = r1;
}

// ---------------- host ----------------

extern "C" void kernel_launch(void* const* d_in, const int* in_sizes, int n_in,
                              void* d_out, int out_size, void* d_ws, size_t ws_size,
                              hipStream_t stream) {
    const float* h = (const float*)d_in[0];
    const float* gate_w = (const float*)d_in[1];
    const float* wg = (const float*)d_in[2];
    const float* wu = (const float*)d_in[3];
    const float* wd = (const float*)d_in[4];

    float* out = (float*)d_out;                       // results: 8192*1024
    float* lb = out + (size_t)B_TOK * DDIM;           // 1
    float* route = lb + 1;                            // 8192*8

    const size_t SZ_META = 1 << 20;                           // 1 MiB
    const size_t SZ_HB = (size_t)B_TOK * DDIM * 2;            // 16,777,216
    const size_t SZ_W = (size_t)NEXP * DDIM * INTER * 2;      // 46,137,344 per tensor
    const size_t SZ_ACT = (size_t)CAP_SLOTS * INTER * 2;      // 98,041,856
    const size_t NEED = SZ_META + SZ_HB + 2 * SZ_W + SZ_ACT;  // ~198.5 MiB
    if (ws_size < NEED) {
        fprintf(stderr, "kernel_launch: ws too small: %zu < %zu\n", ws_size, NEED);
        return;
    }
    char* ws = (char*)d_ws;
    // meta layout (within first 1 MiB)
    int* counts = (int*)(ws + 0);            // 8
    int* rank = (int*)(ws + 32);             // 8
    int* aoff = (int*)(ws + 64);             // 8
    float* sums = (float*)(ws + 96);         // 8
    int* tile_e = (int*)(ws + 128);          // 136
    int* tile_s0 = (int*)(ws + 1024);        // 136
    int* sel01 = (int*)(ws + 2048);          // 8192
    float2* wpair = (float2*)(ws + 34816);   // 8192
    int* idx = (int*)(ws + 100352);          // 17408
    int2* tslot = (int2*)(ws + 262144);      // 8192 int2 = 64KB

    unsigned short* hb = (unsigned short*)(ws + SZ_META);
    unsigned short* wgT = (unsigned short*)(ws + SZ_META + SZ_HB);
    unsigned short* wuT = (unsigned short*)(ws + SZ_META + SZ_HB + SZ_W);
    unsigned short* act = (unsigned short*)(ws + SZ_META + SZ_HB + 2 * SZ_W);
    unsigned short* wdT = wgT;                               // reuse wgT space AFTER gemm1
    unsigned short* y = wuT;                                 // reuse wuT space AFTER gemm1 (35.6MB < 44MB)

    hipMemsetAsync(ws, 0, SZ_META, stream);

    transpose_convert_v2<<<dim3(INTER / 64, DDIM / 64, NEXP), 256, 0, stream>>>(wg, wgT, DDIM, INTER);
    transpose_convert_v2<<<dim3(INTER / 64, DDIM / 64, NEXP), 256, 0, stream>>>(wu, wuT, DDIM, INTER);

    gating_kernel<<<B_TOK / 4, 256, 0, stream>>>(h, gate_w, route, sel01, wpair, counts, sums, hb);
    setup_kernel<<<1, 256, 0, stream>>>(counts, sums, aoff, tile_e, tile_s0, lb);
    fill_kernel<<<B_TOK / 256, 256, 0, stream>>>(sel01, aoff, rank, idx, tslot);

    gemm1_sparse<<<dim3(CAP_TILES, INTER / 128), 256, 0, stream>>>(
        hb, wgT, wuT, tile_e, tile_s0, idx, act);

    // now wgT/wuT are dead: transpose wd into wgT's space; y reuses wuT's space
    transpose_convert_v2<<<dim3(DDIM / 64, INTER / 64, NEXP), 256, 0, stream>>>(wd, wdT, INTER, DDIM);

    gemm2_sparse_v3<<<dim3(CAP_TILES, DDIM / 128), 256, 0, stream>>>(
        act, wdT, tile_e, tile_s0, y);

    combine_kernel<<<(B_TOK * 128) / 256, 256, 0, stream>>>(y, tslot, wpair, out);
}